// Round 8
// baseline (630.582 us; speedup 1.0000x reference)
//
#include <hip/hip_runtime.h>

// ---------------------------------------------------------------------------
// SerializedAttention on MI355X (gfx950), bf16 MFMA pipeline.
// N=65536, B=4, C=512, K=256 (patch), H=8, dh=64, n_chunks=256, tokens=257.
// R7: fix R6's cross-wave race: each phase's covering vmcnt now precedes the
//     CLOSING barrier of the prior phase (vmcnt -> barrier -> ds_read), per
//     the HK discipline. vmcnt is per-wave; only [every-wave vmcnt -> barrier]
//     makes staged LDS readable by other waves. FIFO: prologue 8-out ->
//     VMC(4)+bar; phases 0,1,3 close with VMC(4); epilogue drains 4->2->0.
// ---------------------------------------------------------------------------

typedef float  floatx4 __attribute__((ext_vector_type(4)));
typedef __bf16 bf16x8  __attribute__((ext_vector_type(8)));

__device__ __forceinline__ __bf16 f2bf(float x) {
  unsigned u = __builtin_bit_cast(unsigned, x);
  u = u + 0x7FFFu + ((u >> 16) & 1u);                // RNE
  unsigned short h = (unsigned short)(u >> 16);
  return __builtin_bit_cast(__bf16, h);
}

__device__ __forceinline__ floatx4 mfma_16x16x32(bf16x8 a, bf16x8 b, floatx4 c) {
  return __builtin_amdgcn_mfma_f32_16x16x32_bf16(a, b, c, 0, 0, 0);
}

// async global->LDS, 16B per lane; global addr per-lane, LDS dest = uniform base + lane*16
__device__ __forceinline__ void gload16(const void* g, void* l) {
  __builtin_amdgcn_global_load_lds(
      (const __attribute__((address_space(1))) unsigned int*)g,
      (__attribute__((address_space(3))) unsigned int*)l, 16, 0, 0);
}

// ---------------------------------------------------------------------------
// cast + gather: dst[m][0:512] = bf16(feat[order[m]][0:512])   (serial order)
// ---------------------------------------------------------------------------
__global__ void cast_gather_feat(const float* __restrict__ feat,
                                 const int* __restrict__ order,
                                 __bf16* __restrict__ dst) {
  long i = ((long)blockIdx.x * blockDim.x + threadIdx.x) * 8;
  int row = (int)(i >> 9);
  int col = (int)(i & 511);
  const float* sp = feat + (long)order[row] * 512 + col;
  float4 a = *(const float4*)sp;
  float4 b = *(const float4*)(sp + 4);
  bf16x8 o;
  o[0] = f2bf(a.x); o[1] = f2bf(a.y); o[2] = f2bf(a.z); o[3] = f2bf(a.w);
  o[4] = f2bf(b.x); o[5] = f2bf(b.y); o[6] = f2bf(b.z); o[7] = f2bf(b.w);
  *(bf16x8*)(dst + i) = o;
}

// Wt[n][k] = bf16(W[k][n]) via 32x32 LDS tile (coalesced both sides).
__global__ void transpose_cast(const float* __restrict__ W, __bf16* __restrict__ Wt,
                               int K, int N) {
  __shared__ float tile[32][33];
  const int n0 = blockIdx.x * 32, k0 = blockIdx.y * 32;
  const int c = threadIdx.x & 31, r8 = threadIdx.x >> 5;
#pragma unroll
  for (int i = 0; i < 4; ++i) {
    int r = r8 + i * 8;
    tile[r][c] = W[(long)(k0 + r) * N + n0 + c];
  }
  __syncthreads();
#pragma unroll
  for (int i = 0; i < 4; ++i) {
    int r = r8 + i * 8;
    Wt[(long)(n0 + r) * K + k0 + c] = f2bf(tile[c][r]);
  }
}

// cls_qkv[b][n] = bf16( cls_tokens[b] . Wqkv[:,n] + bqkv[n] ); k-split x4.
__global__ void cls_qkv_kernel(const float* __restrict__ cls_tokens,
                               const float* __restrict__ Wqkv,
                               const float* __restrict__ bqkv,
                               __bf16* __restrict__ clsqkv, int N3) {
  __shared__ float red[256];
  const int c = threadIdx.x & 63, part = threadIdx.x >> 6;
  const int o = blockIdx.x * 64 + c;
  const int b = o / N3, n = o - b * N3;
  float sv = 0.f;
  const int kst = part * 128;
  for (int k = kst; k < kst + 128; ++k)
    sv += cls_tokens[b * 512 + k] * Wqkv[(long)k * N3 + n];
  red[threadIdx.x] = sv;
  __syncthreads();
  if (part == 0)
    clsqkv[o] = f2bf(red[c] + red[c + 64] + red[c + 128] + red[c + 192] + bqkv[n]);
}

// ---------------------------------------------------------------------------
// 256x256 QKV GEMM, BK=64, 8 waves, double-buffered LDS, phase schedule.
// Per-wave FIFO (2 loads/half, stage order A-lo,B-lo,B-hi,A-hi):
//   tile-top: 4 outstanding (B-hi,A-hi of cur)   [after VMC(4)+bar]
//   R0: read(A-lo,B-lo) stage A-lo' -> 6; close VMC(4) retires B-hi
//   R1: read(A-lo,B-hi) stage B-lo' -> 6; close VMC(4) retires A-hi
//   R2: read(A-hi,B-lo) stage B-hi' -> 6; close (no VMC)
//   R3: read(A-hi,B-hi) stage A-hi' -> 8; close VMC(4) retires A-lo',B-lo'
// Every ds_read is after a barrier that follows every wave's covering vmcnt.
// Every LDS overwrite is >=2 barriers after the last read of old content.
// ---------------------------------------------------------------------------
#define LOAD_FRAGS(BUF, QA, QB)                                               \
  do {                                                                        \
    _Pragma("unroll") for (int mi = 0; mi < 4; ++mi) {                        \
      const int row = (QA) * 128 + wm2 * 64 + mi * 16 + l15;                  \
      _Pragma("unroll") for (int ks = 0; ks < 2; ++ks) {                      \
        const int c8 = ks * 4 + quad;                                         \
        af[mi][ks] =                                                          \
            *(const bf16x8*)(&As[BUF][row * 64 + ((c8 ^ (row & 7)) << 3)]);   \
      }                                                                       \
    }                                                                         \
    _Pragma("unroll") for (int ni = 0; ni < 2; ++ni) {                        \
      const int row = (QB) * 128 + wn2 * 32 + ni * 16 + l15;                  \
      _Pragma("unroll") for (int ks = 0; ks < 2; ++ks) {                      \
        const int c8 = ks * 4 + quad;                                         \
        bfr[ni][ks] =                                                         \
            *(const bf16x8*)(&Bs[BUF][row * 64 + ((c8 ^ (row & 7)) << 3)]);   \
      }                                                                       \
    }                                                                         \
  } while (0)

#define MFMA_BODY(QA, QB)                                                     \
  do {                                                                        \
    __builtin_amdgcn_s_barrier();                                             \
    asm volatile("s_waitcnt lgkmcnt(0)" ::: "memory");                        \
    __builtin_amdgcn_sched_barrier(0);                                        \
    __builtin_amdgcn_s_setprio(1);                                            \
    _Pragma("unroll") for (int mi = 0; mi < 4; ++mi)                          \
        _Pragma("unroll") for (int ni = 0; ni < 2; ++ni)                      \
            _Pragma("unroll") for (int ks = 0; ks < 2; ++ks)                  \
                acc[(QA) * 4 + mi][(QB) * 2 + ni] = mfma_16x16x32(            \
                    af[mi][ks], bfr[ni][ks], acc[(QA) * 4 + mi][(QB) * 2 + ni]); \
    __builtin_amdgcn_s_setprio(0);                                            \
  } while (0)

#define VMC(N) asm volatile("s_waitcnt vmcnt(" #N ")" ::: "memory")
#define BAR()  __builtin_amdgcn_s_barrier()

__global__ __launch_bounds__(512, 2) void gemm_qkv_8p(
    const __bf16* __restrict__ A,   // featb [65536][512]
    const __bf16* __restrict__ Bt,  // wqkvT [1536][512]
    const float* __restrict__ bias,
    __bf16* __restrict__ C, int N, int K) {  // 1536, 512
  __shared__ __align__(16) __bf16 As[2][256 * 64];
  __shared__ __align__(16) __bf16 Bs[2][256 * 64];
  const int tid = threadIdx.x;
  const int wave = tid >> 6, lane = tid & 63;
  const int quad = lane >> 4, l15 = lane & 15;
  const int wm2 = wave >> 2, wn2 = wave & 3;       // 2 x 4 wave grid
  // XCD-chunked bijective swizzle: 1536 blocks -> 192/XCD, col-fast (6 cols)
  const int per = gridDim.x >> 3;
  const int work = (blockIdx.x & 7) * per + (blockIdx.x >> 3);
  const int rowblk = work / 6, colblk = work - rowblk * 6;
  const long m0 = (long)rowblk * 256;
  const int n0 = colblk * 256;
  const int srow8 = lane >> 3, sc8p = lane & 7;
  const int NT = K / 64;  // 8

  // stage one half (128 rows) of A or B for k-tile t into buffer b (2 loads/thread)
  auto stageA = [&](int b, int rh, int t) {
#pragma unroll
    for (int j = 0; j < 2; ++j) {
      const int rbase = rh * 128 + j * 64 + wave * 8;
      const int row = rbase + srow8;
      const int c8 = sc8p ^ (row & 7);
      gload16(A + (m0 + row) * K + t * 64 + c8 * 8, &As[b][rbase * 64]);
    }
  };
  auto stageB = [&](int b, int rh, int t) {
#pragma unroll
    for (int j = 0; j < 2; ++j) {
      const int rbase = rh * 128 + j * 64 + wave * 8;
      const int row = rbase + srow8;
      const int c8 = sc8p ^ (row & 7);
      gload16(Bt + (long)(n0 + row) * K + t * 64 + c8 * 8, &Bs[b][rbase * 64]);
    }
  };

  floatx4 acc[8][4];
#pragma unroll
  for (int i = 0; i < 8; ++i)
#pragma unroll
    for (int j = 0; j < 4; ++j) acc[i][j] = floatx4{0.f, 0.f, 0.f, 0.f};

  // prologue: tile 0's halves in FIFO need-order; cover A-lo,B-lo then barrier
  stageA(0, 0, 0); stageB(0, 0, 0); stageB(0, 1, 0); stageA(0, 1, 0);  // 8 out
  VMC(4);
  BAR();

  for (int t = 0; t < NT - 1; ++t) {
    const int cur = t & 1, nxt = cur ^ 1;
    bf16x8 af[4][2], bfr[2][2];
    // R0: quad (0,0); stage A-lo of t+1
    LOAD_FRAGS(cur, 0, 0);
    stageA(nxt, 0, t + 1);
    MFMA_BODY(0, 0);
    VMC(4);  // retire B-hi(cur) for R1
    BAR();
    // R1: quad (0,1); stage B-lo of t+1
    LOAD_FRAGS(cur, 0, 1);
    stageB(nxt, 0, t + 1);
    MFMA_BODY(0, 1);
    VMC(4);  // retire A-hi(cur) for R2
    BAR();
    // R2: quad (1,0); stage B-hi of t+1
    LOAD_FRAGS(cur, 1, 0);
    stageB(nxt, 1, t + 1);
    MFMA_BODY(1, 0);
    BAR();   // R3 needs nothing new
    // R3: quad (1,1); stage A-hi of t+1
    LOAD_FRAGS(cur, 1, 1);
    stageA(nxt, 1, t + 1);
    MFMA_BODY(1, 1);
    VMC(4);  // retire A-lo,B-lo of t+1 for next R0
    BAR();
  }
  {  // epilogue tile NT-1: no staging; drain 4 -> 2 -> 0
    const int cur = (NT - 1) & 1;
    bf16x8 af[4][2], bfr[2][2];
    LOAD_FRAGS(cur, 0, 0);
    MFMA_BODY(0, 0);
    VMC(2);  // retire B-hi
    BAR();
    LOAD_FRAGS(cur, 0, 1);
    MFMA_BODY(0, 1);
    VMC(0);  // retire A-hi
    BAR();
    LOAD_FRAGS(cur, 1, 0);
    MFMA_BODY(1, 0);
    BAR();
    LOAD_FRAGS(cur, 1, 1);
    MFMA_BODY(1, 1);
  }

  // epilogue C-write (bf16 + bias)
#pragma unroll
  for (int mg = 0; mg < 8; ++mg) {
#pragma unroll
    for (int ng = 0; ng < 4; ++ng) {
      const int col = n0 + (ng >> 1) * 128 + wn2 * 32 + (ng & 1) * 16 + l15;
      const float bb = bias[col];
#pragma unroll
      for (int r = 0; r < 4; ++r) {
        const long row =
            m0 + (mg >> 2) * 128 + wm2 * 64 + (mg & 3) * 16 + quad * 4 + r;
        C[row * N + col] = f2bf(acc[mg][ng][r] + bb);
      }
    }
  }
}

// ---------------------------------------------------------------------------
// GEMM: C[m][n] = sum_k A[m][k] * Bt[n][k]  (+bias[n]); 128x128 tile, BK=64.
// 1-D grid, XCD-chunked bijective swizzle, col-fast within chunk.
// ---------------------------------------------------------------------------
template <int OUT_F32, int COLS>
__global__ __launch_bounds__(256, 2) void gemm_bt(
    const __bf16* __restrict__ A, const __bf16* __restrict__ Bt,
    const float* __restrict__ bias, void* __restrict__ C,
    int N, int K) {
  __shared__ __align__(16) __bf16 As[128 * 64];
  __shared__ __align__(16) __bf16 Bs[128 * 64];
  const int tid = threadIdx.x;
  const int wave = tid >> 6, lane = tid & 63;
  const int quad = lane >> 4, l15 = lane & 15;
  const int wr = wave >> 1, wc = wave & 1;
  const int per = gridDim.x >> 3;
  const int work = (blockIdx.x & 7) * per + (blockIdx.x >> 3);
  const int rowblk = work / COLS, colblk = work - rowblk * COLS;
  const long m0 = (long)rowblk * 128;
  const int n0 = colblk * 128;
  const int srow8 = lane >> 3;
  const int sc8p = lane & 7;

  floatx4 zero = {0.f, 0.f, 0.f, 0.f};
  floatx4 acc[4][4];
#pragma unroll
  for (int i = 0; i < 4; ++i)
#pragma unroll
    for (int j = 0; j < 4; ++j) acc[i][j] = zero;

  for (int kt = 0; kt < K; kt += 64) {
    __syncthreads();
#pragma unroll
    for (int i = 0; i < 4; ++i) {
      const int rbase = i * 32 + wave * 8;
      const int row = rbase + srow8;
      const int c8 = sc8p ^ (row & 7);
      gload16(A + (m0 + row) * K + kt + c8 * 8, As + rbase * 64);
      gload16(Bt + (long)(n0 + row) * K + kt + c8 * 8, Bs + rbase * 64);
    }
    __syncthreads();
#pragma unroll
    for (int ks = 0; ks < 2; ++ks) {
      bf16x8 af[4], bfr[4];
#pragma unroll
      for (int mi = 0; mi < 4; ++mi) {
        int row = wr * 64 + mi * 16 + l15;
        int c8 = ks * 4 + quad;
        af[mi] = *(const bf16x8*)(As + row * 64 + ((c8 ^ (row & 7)) << 3));
      }
#pragma unroll
      for (int ni = 0; ni < 4; ++ni) {
        int row = wc * 64 + ni * 16 + l15;
        int c8 = ks * 4 + quad;
        bfr[ni] = *(const bf16x8*)(Bs + row * 64 + ((c8 ^ (row & 7)) << 3));
      }
#pragma unroll
      for (int mi = 0; mi < 4; ++mi)
#pragma unroll
        for (int ni = 0; ni < 4; ++ni)
          acc[mi][ni] = mfma_16x16x32(af[mi], bfr[ni], acc[mi][ni]);
    }
  }
#pragma unroll
  for (int mi = 0; mi < 4; ++mi) {
#pragma unroll
    for (int ni = 0; ni < 4; ++ni) {
      const int col = n0 + wc * 64 + ni * 16 + l15;
      const float bb = bias[col];
#pragma unroll
      for (int r = 0; r < 4; ++r) {
        const long row = m0 + wr * 64 + mi * 16 + quad * 4 + r;
        float v = acc[mi][ni][r] + bb;
        if (OUT_F32)
          ((float*)C)[row * N + col] = v;
        else
          ((__bf16*)C)[row * N + col] = f2bf(v);
      }
    }
  }
}

// ---------------------------------------------------------------------------
// Attention: one block per (chunk, head). 257 tokens (0=cls), 17 key tiles.
// ---------------------------------------------------------------------------
__global__ __launch_bounds__(256, 2) void attn_kernel(
    const __bf16* __restrict__ qkv,     // [65536][1536] serial order
    const __bf16* __restrict__ clsqkv,  // [4][1536]
    const int* __restrict__ order,      // [65536]
    const int* __restrict__ offset,     // [B]
    __bf16* __restrict__ outO,          // [65536][512] original order
    float* __restrict__ outcls,         // [256][512]
    int B) {
  __shared__ __align__(16) __bf16 Ks[272 * 64];        // K rows, stride 64 halves
  __shared__ __align__(16) __bf16 Vt[64 * 264 + 64];   // V^T, skewed rows
  __shared__ __align__(16) __bf16 Pbuf[4 * 16 * 40];
  const int chunk = blockIdx.x & 255;
  const int h = blockIdx.x >> 8;
  const int tid = threadIdx.x;
  const int wave = tid >> 6, lane = tid & 63;
  const int quad = lane >> 4, l15 = lane & 15;
  const int cs = chunk << 8;
  int batch = 0;
  for (int b = 0; b < B; ++b) batch += (offset[b] <= cs) ? 1 : 0;
  const unsigned clsoff =
      (unsigned)((const char*)(clsqkv + (long)batch * 1536) - (const char*)qkv);

  const int qoffB = h * 128;
  const int koffB = 1024 + h * 128;
  const int voffB = 2048 + h * 128;

  // token-row t (0=cls, 1..256 = chunk rows, >=257 dup last) -> byte offset
  auto rowoff = [&](int t) -> unsigned {
    int tt = (t <= 256) ? t : 256;
    return (tt == 0) ? clsoff : (unsigned)(cs + tt - 1) * 3072u;
  };

  // ---- stage Ks: 8 rows (1024B) per wave-issue; slot c8 holds chunk c8^(r&7)
  {
    const int rsub = lane >> 3, c8 = lane & 7;
    for (int i = wave; i < 34; i += 4) {
      int r = i * 8 + rsub;
      gload16((const char*)qkv + rowoff(r) + koffB + ((c8 ^ (r & 7)) << 4),
              Ks + i * 512);
    }
  }

  // ---- stage Vt (transpose, skewed rows): Vt[skew(d) + t] = V[t][d] ----
  {
    const int rsub = lane >> 3, c8 = lane & 7;
#pragma unroll
    for (int p = 0; p < 8; ++p) {
      int t = p * 32 + wave * 8 + rsub;  // token 0..255
      unsigned ro = (t == 0) ? clsoff : (unsigned)(cs + t - 1) * 3072u;
      bf16x8 v = *(const bf16x8*)((const char*)qkv + ro + voffB + c8 * 16);
#pragma unroll
      for (int j = 0; j < 8; ++j)
        Vt[(c8 * 8 + j) * 264 + c8 * 8 + t] = v[j];   // skew = 8*((d>>3)&7)
    }
    if (tid < 8) {  // token 256
      bf16x8 v = *(const bf16x8*)((const char*)qkv +
                                  (unsigned)(cs + 255) * 3072u + voffB + tid * 16);
#pragma unroll
      for (int j = 0; j < 8; ++j)
        Vt[(tid * 8 + j) * 264 + tid * 8 + 256] = v[j];
    }
  }
  __syncthreads();   // drains vmcnt (global_load_lds) + lgkmcnt

  // per-lane constants
  int vbase[4];
#pragma unroll
  for (int ni = 0; ni < 4; ++ni) {
    int d = ni * 16 + l15;
    vbase[ni] = d * 264 + ((ni * 2 + (l15 >> 3)) & 7) * 8;
  }
  float v256[4];
#pragma unroll
  for (int ni = 0; ni < 4; ++ni) v256[ni] = (float)Vt[vbase[ni] + 256];
  __bf16* Pw = Pbuf + wave * (16 * 40);
  const int sw = l15 & 7;                       // (row&7) for K frag reads
  const __bf16* kb = Ks + l15 * 64;

  for (int rt = wave; rt < 17; rt += 4) {
    const unsigned qo = rowoff(rt * 16 + l15);
    bf16x8 qf0 = *(const bf16x8*)((const char*)qkv + qo + qoffB + quad * 16);
    bf16x8 qf1 = *(const bf16x8*)((const char*)qkv + qo + qoffB + 64 + quad * 16);

    floatx4 zero = {0.f, 0.f, 0.f, 0.f};
    floatx4 s[17];
#pragma unroll
    for (int i = 0; i < 17; ++i) s[i] = zero;
#pragma unroll
    for (int k2 = 0; k2 < 17; ++k2) {
      const __bf16* kr = kb + k2 * 1024;
      bf16x8 kf0 = *(const bf16x8*)(kr + ((quad ^ sw) << 3));
      bf16x8 kf1 = *(const bf16x8*)(kr + (((quad + 4) ^ sw) << 3));
      s[k2] = mfma_16x16x32(qf0, kf0, s[k2]);
      s[k2] = mfma_16x16x32(qf1, kf1, s[k2]);
    }

    // ---- softmax (scale folded into exp2; mask only tile 16) ----
    float mx[4] = {-3.0e38f, -3.0e38f, -3.0e38f, -3.0e38f};
#pragma unroll
    for (int k2 = 0; k2 < 16; ++k2)
#pragma unroll
      for (int r = 0; r < 4; ++r) mx[r] = fmaxf(mx[r], s[k2][r]);
#pragma unroll
    for (int r = 0; r < 4; ++r) {
      float v = (l15 == 0) ? s[16][r] : -3.0e38f;
      s[16][r] = v;
      mx[r] = fmaxf(mx[r], v);
    }
#pragma unroll
    for (int off = 1; off < 16; off <<= 1)
#pragma unroll
      for (int r = 0; r < 4; ++r) mx[r] = fmaxf(mx[r], __shfl_xor(mx[r], off, 16));
    const float c1 = 0.125f * 1.44269504f;  // scale * log2(e)
    float mb[4], sum[4] = {0.f, 0.f, 0.f, 0.f};
#pragma unroll
    for (int r = 0; r < 4; ++r) mb[r] = mx[r] * c1;
#pragma unroll
    for (int k2 = 0; k2 < 17; ++k2)
#pragma unroll
      for (int r = 0; r < 4; ++r) {
        float e = __builtin_amdgcn_exp2f(fmaf(s[k2][r], c1, -mb[r]));
        s[k2][r] = e;
        sum[r] += e;
      }
#pragma unroll
    for (int off = 1; off < 16; off <<= 1)
#pragma unroll
      for (int r = 0; r < 4; ++r) sum[r] += __shfl_xor(sum[r], off, 16);
    float rl[4];
#pragma unroll
    for (int r = 0; r < 4; ++r) rl[r] = 1.0f / sum[r];

    // ---- PV: keys 0..255 via MFMA (unnormalized P), key 256 scalar ----
    floatx4 o[4];
#pragma unroll
    for (int i = 0; i < 4; ++i) o[i] = zero;
#pragma unroll
    for (int ks = 0; ks < 8; ++ks) {
#pragma unroll
      for (int half = 0; half < 2; ++half) {
        int kt2 = ks * 2 + half;
#pragma unroll
        for (int r = 0; r < 4; ++r)
          Pw[(quad * 4 + r) * 40 + half * 16 + l15] = f2bf(s[kt2][r]);
      }
      asm volatile("s_waitcnt lgkmcnt(0)" ::: "memory");
      bf16x8 pf = *(const bf16x8*)(Pw + l15 * 40 + quad * 8);
#pragma unroll
      for (int ni = 0; ni < 4; ++ni) {
        bf16x8 vf = *(const bf16x8*)(Vt + vbase[ni] + ks * 32 + quad * 8);
        o[ni] = mfma_16x16x32(pf, vf, o[ni]);
      }
    }
    float p256[4];
#pragma unroll
    for (int r = 0; r < 4; ++r) p256[r] = __shfl(s[16][r], lane & 48, 64);
#pragma unroll
    for (int ni = 0; ni < 4; ++ni)
#pragma unroll
      for (int r = 0; r < 4; ++r)
        o[ni][r] = (o[ni][r] + p256[r] * v256[ni]) * rl[r];

    // ---- store ----
#pragma unroll
    for (int r = 0; r < 4; ++r) {
      int q = rt * 16 + quad * 4 + r;
      if (q > 256) continue;
      if (q == 0) {
#pragma unroll
        for (int ni = 0; ni < 4; ++ni)
          outcls[(long)chunk * 512 + h * 64 + ni * 16 + l15] = o[ni][r];
      } else {
        long orow = (long)order[cs + q - 1];
#pragma unroll
        for (int ni = 0; ni < 4; ++ni)
          outO[orow * 512 + h * 64 + ni * 16 + l15] = f2bf(o[ni][r]);
      }
    }
  }
}

// cls_feat[b][c] = mean over batch-b chunks of outcls[chunk][c]
__global__ void cls_feat_kernel(const float* __restrict__ outcls,
                                const int* __restrict__ offset,
                                float* __restrict__ dst, int B, int C) {
  int i = blockIdx.x * blockDim.x + threadIdx.x;
  if (i >= B * C) return;
  int b = i / C, c = i - b * C;
  int st = (b == 0) ? 0 : offset[b - 1];
  int en = offset[b];
  int c0 = st >> 8, c1 = en >> 8;
  float s = 0.f;
  for (int ch = c0; ch < c1; ++ch) s += outcls[(long)ch * C + c];
  dst[i] = s / (float)(c1 - c0);
}

// ---------------------------------------------------------------------------
extern "C" void kernel_launch(void* const* d_in, const int* in_sizes, int n_in,
                              void* d_out, int out_size, void* d_ws, size_t ws_size,
                              hipStream_t stream) {
  const float* feat       = (const float*)d_in[0];
  const float* cls_tokens = (const float*)d_in[1];
  const float* Wqkv       = (const float*)d_in[2];
  const float* bqkv       = (const float*)d_in[3];
  const float* Wproj      = (const float*)d_in[4];
  const float* bproj      = (const float*)d_in[5];
  const int*   order      = (const int*)d_in[6];
  const int*   offset     = (const int*)d_in[8];
  const int B = in_sizes[8];  // 4

  char* ws = (char*)d_ws;
  __bf16* qkv    = (__bf16*)(ws);                   // 65536*1536*2 = 201326592
  __bf16* featb  = (__bf16*)(ws + 201326592);       // 65536*512*2  =  67108864
  __bf16* outO   = featb;                           // reuse after gemm1
  __bf16* wqkvT  = (__bf16*)(ws + 268435456);       // 1536*512*2
  __bf16* wprojT = (__bf16*)(ws + 270008320);       // 512*512*2
  __bf16* clsqkv = (__bf16*)(ws + 270532608);       // 4*1536*2
  float*  outcls = (float*)(ws + 270544896);        // 256*512*4

  float* feat_out = (float*)d_out;
  float* cls_out  = feat_out + (long)65536 * 512;

  cast_gather_feat<<<16384, 256, 0, stream>>>(feat, order, featb);
  transpose_cast<<<dim3(48, 16), 256, 0, stream>>>(Wqkv, wqkvT, 512, 1536);
  transpose_cast<<<dim3(16, 16), 256, 0, stream>>>(Wproj, wprojT, 512, 512);
  cls_qkv_kernel<<<96, 256, 0, stream>>>(cls_tokens, Wqkv, bqkv, clsqkv, 1536);

  // QKV GEMM: 256x256 tile, race-fixed phase schedule; 1536 blocks (256r x 6c)
  gemm_qkv_8p<<<1536, 512, 0, stream>>>(featb, wqkvT, bqkv, qkv, 1536, 512);

  attn_kernel<<<2048, 256, 0, stream>>>(qkv, clsqkv, order, offset, outO, outcls, B);

  // proj GEMM: 2048 blocks (512 row x 4 col), XCD swizzle
  gemm_bt<1, 4><<<2048, 256, 0, stream>>>(outO, wprojT, bproj, (void*)feat_out, 512, 512);

  cls_feat_kernel<<<8, 256, 0, stream>>>(outcls, offset, cls_out, B, 512);
}

// Round 9
// 590.498 us; speedup vs baseline: 1.0679x; 1.0679x over previous
//
#include <hip/hip_runtime.h>

// ---------------------------------------------------------------------------
// SerializedAttention on MI355X (gfx950), bf16 MFMA pipeline.
// N=65536, B=4, C=512, K=256 (patch), H=8, dh=64, n_chunks=256, tokens=257.
// R8: PERMANENT REVERT to the R4 build (594.3us, session best).
//     Phase-schedule arc (R5-R7) condemned: at K=512 there are only 8 K-tiles
//     per block -> the 256x256 counted-vmcnt pipeline never amortizes its
//     prologue/barrier overhead (template validated at 64-128 K-tiles), and
//     128KB LDS (1 block/CU) kills the inter-block overlap that lets the
//     2-barrier structure reach 794 TF here. Both correct variants measured
//     SLOWER (164/172us vs 130us).
//     Kept: XCD-chunked bijective block swizzle on both GEMMs
//     (FETCH 266->47MB measured).
// ---------------------------------------------------------------------------

typedef float  floatx4 __attribute__((ext_vector_type(4)));
typedef __bf16 bf16x8  __attribute__((ext_vector_type(8)));

__device__ __forceinline__ __bf16 f2bf(float x) {
  unsigned u = __builtin_bit_cast(unsigned, x);
  u = u + 0x7FFFu + ((u >> 16) & 1u);                // RNE
  unsigned short h = (unsigned short)(u >> 16);
  return __builtin_bit_cast(__bf16, h);
}

__device__ __forceinline__ floatx4 mfma_16x16x32(bf16x8 a, bf16x8 b, floatx4 c) {
  return __builtin_amdgcn_mfma_f32_16x16x32_bf16(a, b, c, 0, 0, 0);
}

// async global->LDS, 16B per lane; global addr per-lane, LDS dest = uniform base + lane*16
__device__ __forceinline__ void gload16(const void* g, void* l) {
  __builtin_amdgcn_global_load_lds(
      (const __attribute__((address_space(1))) unsigned int*)g,
      (__attribute__((address_space(3))) unsigned int*)l, 16, 0, 0);
}

// ---------------------------------------------------------------------------
// cast + gather: dst[m][0:512] = bf16(feat[order[m]][0:512])   (serial order)
// ---------------------------------------------------------------------------
__global__ void cast_gather_feat(const float* __restrict__ feat,
                                 const int* __restrict__ order,
                                 __bf16* __restrict__ dst) {
  long i = ((long)blockIdx.x * blockDim.x + threadIdx.x) * 8;
  int row = (int)(i >> 9);
  int col = (int)(i & 511);
  const float* sp = feat + (long)order[row] * 512 + col;
  float4 a = *(const float4*)sp;
  float4 b = *(const float4*)(sp + 4);
  bf16x8 o;
  o[0] = f2bf(a.x); o[1] = f2bf(a.y); o[2] = f2bf(a.z); o[3] = f2bf(a.w);
  o[4] = f2bf(b.x); o[5] = f2bf(b.y); o[6] = f2bf(b.z); o[7] = f2bf(b.w);
  *(bf16x8*)(dst + i) = o;
}

// Wt[n][k] = bf16(W[k][n]) via 32x32 LDS tile (coalesced both sides).
__global__ void transpose_cast(const float* __restrict__ W, __bf16* __restrict__ Wt,
                               int K, int N) {
  __shared__ float tile[32][33];
  const int n0 = blockIdx.x * 32, k0 = blockIdx.y * 32;
  const int c = threadIdx.x & 31, r8 = threadIdx.x >> 5;
#pragma unroll
  for (int i = 0; i < 4; ++i) {
    int r = r8 + i * 8;
    tile[r][c] = W[(long)(k0 + r) * N + n0 + c];
  }
  __syncthreads();
#pragma unroll
  for (int i = 0; i < 4; ++i) {
    int r = r8 + i * 8;
    Wt[(long)(n0 + r) * K + k0 + c] = f2bf(tile[c][r]);
  }
}

// cls_qkv[b][n] = bf16( cls_tokens[b] . Wqkv[:,n] + bqkv[n] ); k-split x4.
__global__ void cls_qkv_kernel(const float* __restrict__ cls_tokens,
                               const float* __restrict__ Wqkv,
                               const float* __restrict__ bqkv,
                               __bf16* __restrict__ clsqkv, int N3) {
  __shared__ float red[256];
  const int c = threadIdx.x & 63, part = threadIdx.x >> 6;
  const int o = blockIdx.x * 64 + c;
  const int b = o / N3, n = o - b * N3;
  float sv = 0.f;
  const int kst = part * 128;
  for (int k = kst; k < kst + 128; ++k)
    sv += cls_tokens[b * 512 + k] * Wqkv[(long)k * N3 + n];
  red[threadIdx.x] = sv;
  __syncthreads();
  if (part == 0)
    clsqkv[o] = f2bf(red[c] + red[c + 64] + red[c + 128] + red[c + 192] + bqkv[n]);
}

// ---------------------------------------------------------------------------
// GEMM: C[m][n] = sum_k A[m][k] * Bt[n][k]  (+bias[n]); 128x128 tile, BK=64.
// 1-D grid, XCD-chunked bijective swizzle (grid % 8 == 0), col-fast within
// chunk: the COLS col-blocks sharing an A row-tile run consecutively on the
// SAME XCD -> A row-tile stays L2-hot (R2/R3: FETCH 266->47MB with this map).
// ---------------------------------------------------------------------------
template <int OUT_F32, int COLS>
__global__ __launch_bounds__(256, 2) void gemm_bt(
    const __bf16* __restrict__ A, const __bf16* __restrict__ Bt,
    const float* __restrict__ bias, void* __restrict__ C,
    int N, int K) {
  __shared__ __align__(16) __bf16 As[128 * 64];
  __shared__ __align__(16) __bf16 Bs[128 * 64];
  const int tid = threadIdx.x;
  const int wave = tid >> 6, lane = tid & 63;
  const int quad = lane >> 4, l15 = lane & 15;
  const int wr = wave >> 1, wc = wave & 1;
  const int per = gridDim.x >> 3;
  const int work = (blockIdx.x & 7) * per + (blockIdx.x >> 3);
  const int rowblk = work / COLS, colblk = work - rowblk * COLS;
  const long m0 = (long)rowblk * 128;
  const int n0 = colblk * 128;
  const int srow8 = lane >> 3;
  const int sc8p = lane & 7;

  floatx4 zero = {0.f, 0.f, 0.f, 0.f};
  floatx4 acc[4][4];
#pragma unroll
  for (int i = 0; i < 4; ++i)
#pragma unroll
    for (int j = 0; j < 4; ++j) acc[i][j] = zero;

  for (int kt = 0; kt < K; kt += 64) {
    __syncthreads();
#pragma unroll
    for (int i = 0; i < 4; ++i) {
      const int rbase = i * 32 + wave * 8;
      const int row = rbase + srow8;
      const int c8 = sc8p ^ (row & 7);
      gload16(A + (m0 + row) * K + kt + c8 * 8, As + rbase * 64);
      gload16(Bt + (long)(n0 + row) * K + kt + c8 * 8, Bs + rbase * 64);
    }
    __syncthreads();
#pragma unroll
    for (int ks = 0; ks < 2; ++ks) {
      bf16x8 af[4], bfr[4];
#pragma unroll
      for (int mi = 0; mi < 4; ++mi) {
        int row = wr * 64 + mi * 16 + l15;
        int c8 = ks * 4 + quad;
        af[mi] = *(const bf16x8*)(As + row * 64 + ((c8 ^ (row & 7)) << 3));
      }
#pragma unroll
      for (int ni = 0; ni < 4; ++ni) {
        int row = wc * 64 + ni * 16 + l15;
        int c8 = ks * 4 + quad;
        bfr[ni] = *(const bf16x8*)(Bs + row * 64 + ((c8 ^ (row & 7)) << 3));
      }
#pragma unroll
      for (int mi = 0; mi < 4; ++mi)
#pragma unroll
        for (int ni = 0; ni < 4; ++ni)
          acc[mi][ni] = mfma_16x16x32(af[mi], bfr[ni], acc[mi][ni]);
    }
  }
#pragma unroll
  for (int mi = 0; mi < 4; ++mi) {
#pragma unroll
    for (int ni = 0; ni < 4; ++ni) {
      const int col = n0 + wc * 64 + ni * 16 + l15;
      const float bb = bias[col];
#pragma unroll
      for (int r = 0; r < 4; ++r) {
        const long row = m0 + wr * 64 + mi * 16 + quad * 4 + r;
        float v = acc[mi][ni][r] + bb;
        if (OUT_F32)
          ((float*)C)[row * N + col] = v;
        else
          ((__bf16*)C)[row * N + col] = f2bf(v);
      }
    }
  }
}

// ---------------------------------------------------------------------------
// Attention: one block per (chunk, head). 257 tokens (0=cls), 17 key tiles.
// K staged ONCE into LDS via global_load_lds (XOR chunk swizzle, stride 128B)
// -> S-phase reads are ds_read_b128, no redundant global gathers.
// Vt rows skewed by 8*((d>>3)&7) chunks -> staging writes bank-conflict-free.
// LDS: Ks 34816 + Vt 33920 + Pbuf 5120 = 73856 B -> 2 blocks/CU.
// ---------------------------------------------------------------------------
__global__ __launch_bounds__(256, 2) void attn_kernel(
    const __bf16* __restrict__ qkv,     // [65536][1536] serial order
    const __bf16* __restrict__ clsqkv,  // [4][1536]
    const int* __restrict__ order,      // [65536]
    const int* __restrict__ offset,     // [B]
    __bf16* __restrict__ outO,          // [65536][512] original order
    float* __restrict__ outcls,         // [256][512]
    int B) {
  __shared__ __align__(16) __bf16 Ks[272 * 64];        // K rows, stride 64 halves
  __shared__ __align__(16) __bf16 Vt[64 * 264 + 64];   // V^T, skewed rows
  __shared__ __align__(16) __bf16 Pbuf[4 * 16 * 40];
  const int chunk = blockIdx.x & 255;
  const int h = blockIdx.x >> 8;
  const int tid = threadIdx.x;
  const int wave = tid >> 6, lane = tid & 63;
  const int quad = lane >> 4, l15 = lane & 15;
  const int cs = chunk << 8;
  int batch = 0;
  for (int b = 0; b < B; ++b) batch += (offset[b] <= cs) ? 1 : 0;
  const unsigned clsoff =
      (unsigned)((const char*)(clsqkv + (long)batch * 1536) - (const char*)qkv);

  const int qoffB = h * 128;
  const int koffB = 1024 + h * 128;
  const int voffB = 2048 + h * 128;

  // token-row t (0=cls, 1..256 = chunk rows, >=257 dup last) -> byte offset
  auto rowoff = [&](int t) -> unsigned {
    int tt = (t <= 256) ? t : 256;
    return (tt == 0) ? clsoff : (unsigned)(cs + tt - 1) * 3072u;
  };

  // ---- stage Ks: 8 rows (1024B) per wave-issue; slot c8 holds chunk c8^(r&7)
  {
    const int rsub = lane >> 3, c8 = lane & 7;
    for (int i = wave; i < 34; i += 4) {
      int r = i * 8 + rsub;
      gload16((const char*)qkv + rowoff(r) + koffB + ((c8 ^ (r & 7)) << 4),
              Ks + i * 512);
    }
  }

  // ---- stage Vt (transpose, skewed rows): Vt[skew(d) + t] = V[t][d] ----
  {
    const int rsub = lane >> 3, c8 = lane & 7;
#pragma unroll
    for (int p = 0; p < 8; ++p) {
      int t = p * 32 + wave * 8 + rsub;  // token 0..255
      unsigned ro = (t == 0) ? clsoff : (unsigned)(cs + t - 1) * 3072u;
      bf16x8 v = *(const bf16x8*)((const char*)qkv + ro + voffB + c8 * 16);
#pragma unroll
      for (int j = 0; j < 8; ++j)
        Vt[(c8 * 8 + j) * 264 + c8 * 8 + t] = v[j];   // skew = 8*((d>>3)&7)
    }
    if (tid < 8) {  // token 256
      bf16x8 v = *(const bf16x8*)((const char*)qkv +
                                  (unsigned)(cs + 255) * 3072u + voffB + tid * 16);
#pragma unroll
      for (int j = 0; j < 8; ++j)
        Vt[(tid * 8 + j) * 264 + tid * 8 + 256] = v[j];
    }
  }
  __syncthreads();   // drains vmcnt (global_load_lds) + lgkmcnt

  // per-lane constants
  int vbase[4];
#pragma unroll
  for (int ni = 0; ni < 4; ++ni) {
    int d = ni * 16 + l15;
    vbase[ni] = d * 264 + ((ni * 2 + (l15 >> 3)) & 7) * 8;
  }
  float v256[4];
#pragma unroll
  for (int ni = 0; ni < 4; ++ni) v256[ni] = (float)Vt[vbase[ni] + 256];
  __bf16* Pw = Pbuf + wave * (16 * 40);
  const int sw = l15 & 7;                       // (row&7) for K frag reads
  const __bf16* kb = Ks + l15 * 64;

  for (int rt = wave; rt < 17; rt += 4) {
    const unsigned qo = rowoff(rt * 16 + l15);
    bf16x8 qf0 = *(const bf16x8*)((const char*)qkv + qo + qoffB + quad * 16);
    bf16x8 qf1 = *(const bf16x8*)((const char*)qkv + qo + qoffB + 64 + quad * 16);

    floatx4 zero = {0.f, 0.f, 0.f, 0.f};
    floatx4 s[17];
#pragma unroll
    for (int i = 0; i < 17; ++i) s[i] = zero;
#pragma unroll
    for (int k2 = 0; k2 < 17; ++k2) {
      const __bf16* kr = kb + k2 * 1024;
      bf16x8 kf0 = *(const bf16x8*)(kr + ((quad ^ sw) << 3));
      bf16x8 kf1 = *(const bf16x8*)(kr + (((quad + 4) ^ sw) << 3));
      s[k2] = mfma_16x16x32(qf0, kf0, s[k2]);
      s[k2] = mfma_16x16x32(qf1, kf1, s[k2]);
    }

    // ---- softmax (scale folded into exp2; mask only tile 16) ----
    float mx[4] = {-3.0e38f, -3.0e38f, -3.0e38f, -3.0e38f};
#pragma unroll
    for (int k2 = 0; k2 < 16; ++k2)
#pragma unroll
      for (int r = 0; r < 4; ++r) mx[r] = fmaxf(mx[r], s[k2][r]);
#pragma unroll
    for (int r = 0; r < 4; ++r) {
      float v = (l15 == 0) ? s[16][r] : -3.0e38f;
      s[16][r] = v;
      mx[r] = fmaxf(mx[r], v);
    }
#pragma unroll
    for (int off = 1; off < 16; off <<= 1)
#pragma unroll
      for (int r = 0; r < 4; ++r) mx[r] = fmaxf(mx[r], __shfl_xor(mx[r], off, 16));
    const float c1 = 0.125f * 1.44269504f;  // scale * log2(e)
    float mb[4], sum[4] = {0.f, 0.f, 0.f, 0.f};
#pragma unroll
    for (int r = 0; r < 4; ++r) mb[r] = mx[r] * c1;
#pragma unroll
    for (int k2 = 0; k2 < 17; ++k2)
#pragma unroll
      for (int r = 0; r < 4; ++r) {
        float e = __builtin_amdgcn_exp2f(fmaf(s[k2][r], c1, -mb[r]));
        s[k2][r] = e;
        sum[r] += e;
      }
#pragma unroll
    for (int off = 1; off < 16; off <<= 1)
#pragma unroll
      for (int r = 0; r < 4; ++r) sum[r] += __shfl_xor(sum[r], off, 16);
    float rl[4];
#pragma unroll
    for (int r = 0; r < 4; ++r) rl[r] = 1.0f / sum[r];

    // ---- PV: keys 0..255 via MFMA (unnormalized P), key 256 scalar ----
    floatx4 o[4];
#pragma unroll
    for (int i = 0; i < 4; ++i) o[i] = zero;
#pragma unroll
    for (int ks = 0; ks < 8; ++ks) {
#pragma unroll
      for (int half = 0; half < 2; ++half) {
        int kt2 = ks * 2 + half;
#pragma unroll
        for (int r = 0; r < 4; ++r)
          Pw[(quad * 4 + r) * 40 + half * 16 + l15] = f2bf(s[kt2][r]);
      }
      asm volatile("s_waitcnt lgkmcnt(0)" ::: "memory");
      bf16x8 pf = *(const bf16x8*)(Pw + l15 * 40 + quad * 8);
#pragma unroll
      for (int ni = 0; ni < 4; ++ni) {
        bf16x8 vf = *(const bf16x8*)(Vt + vbase[ni] + ks * 32 + quad * 8);
        o[ni] = mfma_16x16x32(pf, vf, o[ni]);
      }
    }
    float p256[4];
#pragma unroll
    for (int r = 0; r < 4; ++r) p256[r] = __shfl(s[16][r], lane & 48, 64);
#pragma unroll
    for (int ni = 0; ni < 4; ++ni)
#pragma unroll
      for (int r = 0; r < 4; ++r)
        o[ni][r] = (o[ni][r] + p256[r] * v256[ni]) * rl[r];

    // ---- store ----
#pragma unroll
    for (int r = 0; r < 4; ++r) {
      int q = rt * 16 + quad * 4 + r;
      if (q > 256) continue;
      if (q == 0) {
#pragma unroll
        for (int ni = 0; ni < 4; ++ni)
          outcls[(long)chunk * 512 + h * 64 + ni * 16 + l15] = o[ni][r];
      } else {
        long orow = (long)order[cs + q - 1];
#pragma unroll
        for (int ni = 0; ni < 4; ++ni)
          outO[orow * 512 + h * 64 + ni * 16 + l15] = f2bf(o[ni][r]);
      }
    }
  }
}

// cls_feat[b][c] = mean over batch-b chunks of outcls[chunk][c]
__global__ void cls_feat_kernel(const float* __restrict__ outcls,
                                const int* __restrict__ offset,
                                float* __restrict__ dst, int B, int C) {
  int i = blockIdx.x * blockDim.x + threadIdx.x;
  if (i >= B * C) return;
  int b = i / C, c = i - b * C;
  int st = (b == 0) ? 0 : offset[b - 1];
  int en = offset[b];
  int c0 = st >> 8, c1 = en >> 8;
  float s = 0.f;
  for (int ch = c0; ch < c1; ++ch) s += outcls[(long)ch * C + c];
  dst[i] = s / (float)(c1 - c0);
}

// ---------------------------------------------------------------------------
extern "C" void kernel_launch(void* const* d_in, const int* in_sizes, int n_in,
                              void* d_out, int out_size, void* d_ws, size_t ws_size,
                              hipStream_t stream) {
  const float* feat       = (const float*)d_in[0];
  const float* cls_tokens = (const float*)d_in[1];
  const float* Wqkv       = (const float*)d_in[2];
  const float* bqkv       = (const float*)d_in[3];
  const float* Wproj      = (const float*)d_in[4];
  const float* bproj      = (const float*)d_in[5];
  const int*   order      = (const int*)d_in[6];
  const int*   offset     = (const int*)d_in[8];
  const int B = in_sizes[8];  // 4

  char* ws = (char*)d_ws;
  __bf16* qkv    = (__bf16*)(ws);                   // 65536*1536*2 = 201326592
  __bf16* featb  = (__bf16*)(ws + 201326592);       // 65536*512*2  =  67108864
  __bf16* outO   = featb;                           // reuse after gemm1
  __bf16* wqkvT  = (__bf16*)(ws + 268435456);       // 1536*512*2
  __bf16* wprojT = (__bf16*)(ws + 270008320);       // 512*512*2
  __bf16* clsqkv = (__bf16*)(ws + 270532608);       // 4*1536*2
  float*  outcls = (float*)(ws + 270544896);        // 256*512*4

  float* feat_out = (float*)d_out;
  float* cls_out  = feat_out + (long)65536 * 512;

  cast_gather_feat<<<16384, 256, 0, stream>>>(feat, order, featb);
  transpose_cast<<<dim3(48, 16), 256, 0, stream>>>(Wqkv, wqkvT, 512, 1536);
  transpose_cast<<<dim3(16, 16), 256, 0, stream>>>(Wproj, wprojT, 512, 512);
  cls_qkv_kernel<<<96, 256, 0, stream>>>(cls_tokens, Wqkv, bqkv, clsqkv, 1536);

  // QKV GEMM: 6144 blocks (512 row x 12 col), XCD-chunked col-fast swizzle
  gemm_bt<0, 12><<<6144, 256, 0, stream>>>(featb, wqkvT, bqkv, (void*)qkv, 1536, 512);

  attn_kernel<<<2048, 256, 0, stream>>>(qkv, clsqkv, order, offset, outO, outcls, B);

  // proj GEMM: 2048 blocks (512 row x 4 col), same swizzle
  gemm_bt<1, 4><<<2048, 256, 0, stream>>>(outO, wprojT, bproj, (void*)feat_out, 512, 512);

  cls_feat_kernel<<<8, 256, 0, stream>>>(outcls, offset, cls_out, B, 512);
}